// Round 5
// baseline (221.107 us; speedup 1.0000x reference)
//
#include <hip/hip_runtime.h>
#include <hip/hip_bf16.h>
#include <math.h>

#define BDIM 512
#define DDIM 512
#define CDIM 100000
#define NC 64
#define BK 64
#define NSLICE (DDIM / BK)              // 8
#define NCHUNK ((CDIM + NC - 1) / NC)   // 1563

typedef __attribute__((ext_vector_type(8))) short short8;
typedef __attribute__((ext_vector_type(4))) float f32x4;

__device__ __forceinline__ unsigned short f2bf(float f) {
  unsigned int u = __builtin_bit_cast(unsigned int, f);
  u = (u + 0x7FFFu + ((u >> 16) & 1u)) >> 16;   // RNE
  return (unsigned short)u;
}

// ---- kernel 1: L2-normalize feature rows, emit bf16 [B][D] ----
__global__ void k_rownorm(const float* __restrict__ x, unsigned short* __restrict__ a) {
  const int b = blockIdx.x;
  const int tid = threadIdx.x;
  const float* row = x + (size_t)b * DDIM;
  float v0 = row[tid], v1 = row[tid + 256];
  float ss = v0 * v0 + v1 * v1;
  #pragma unroll
  for (int m = 1; m < 64; m <<= 1) ss += __shfl_xor(ss, m);
  __shared__ float sred[4];
  __shared__ float sinv;
  if ((tid & 63) == 0) sred[tid >> 6] = ss;
  __syncthreads();
  if (tid == 0) {
    float s = sred[0] + sred[1] + sred[2] + sred[3];
    sinv = 1.f / fmaxf(sqrtf(s), 1e-12f);
  }
  __syncthreads();
  const float inv = sinv;
  a[(size_t)b * DDIM + tid] = f2bf(v0 * inv);
  a[(size_t)b * DDIM + tid + 256] = f2bf(v1 * inv);
}

// ---- kernel 2: fused colnorm + GEMM + margin + per-chunk LSE partials ----
// 512 threads / 8 waves; wave owns 64 rows x 64 cols (acc 4x4).
// A fragments read directly from L2-resident bf16 ws (no LDS round-trip,
// imm-offset loads via full s-unroll). B: reg-staged fp32->bf16, conflict-free
// ds_writes, 2x8KB double buffer. LDS ~18.5KB -> multiple blocks/CU for TLP.
__global__ __launch_bounds__(512)
void k_main(const unsigned short* __restrict__ a,
            const float* __restrict__ w,
            const long long* __restrict__ label,
            float2* __restrict__ part,
            float* __restrict__ labellogit) {
  __shared__ __align__(16) unsigned short blds[2][NC * BK];     // 2 x 8 KB
  __shared__ float ssred[8][NC];                                // 2 KB
  __shared__ float invwn_sh[NC];

  const int t = threadIdx.x;
  const int chunk = blockIdx.x;
  const int c0 = chunk * NC;
  const bool tailblk = (c0 + NC > CDIM);

  const int wave = t >> 6;
  const int lane = t & 63;
  const int lhi = lane >> 4;   // 0..3
  const int llo = lane & 15;   // 0..15

  // B staging: thread -> k-pair (2*dgh, 2*dgh+1) x 4 cols
  const int dgh = (t & 127) >> 2;               // 0..31
  const int bc4 = (((t >> 7) << 2) | (t & 3)) * 4;

  float4 p0, p1;   // in-flight w data
  float ssp0 = 0.f, ssp1 = 0.f, ssp2 = 0.f, ssp3 = 0.f;

  auto issueW = [&](int s) {
    const size_t base = (size_t)(s * BK + 2 * dgh) * CDIM + c0 + bc4;
    if (!tailblk) {
      p0 = *reinterpret_cast<const float4*>(w + base);
      p1 = *reinterpret_cast<const float4*>(w + base + CDIM);
    } else {
      #pragma unroll
      for (int j = 0; j < 4; j++) {
        const bool v = (c0 + bc4 + j) < CDIM;
        p0[j] = v ? w[base + j] : 0.f;
        p1[j] = v ? w[base + CDIM + j] : 0.f;
      }
    }
  };
  auto commitW = [&](int buf) {
    ssp0 += p0.x * p0.x + p1.x * p1.x;
    ssp1 += p0.y * p0.y + p1.y * p1.y;
    ssp2 += p0.z * p0.z + p1.z * p1.z;
    ssp3 += p0.w * p0.w + p1.w * p1.w;
    unsigned int* b32 = reinterpret_cast<unsigned int*>(&blds[buf][0]);
    #pragma unroll
    for (int j = 0; j < 4; j++) {
      const int c = bc4 + j;
      const unsigned int pk = (unsigned int)f2bf(p0[j]) | ((unsigned int)f2bf(p1[j]) << 16);
      b32[c * 32 + (dgh ^ ((c & 7) << 2))] = pk;
    }
  };

  f32x4 acc[4][4];
  #pragma unroll
  for (int i = 0; i < 4; i++)
    #pragma unroll
    for (int j = 0; j < 4; j++)
      acc[i][j] = (f32x4){0.f, 0.f, 0.f, 0.f};

  // A fragment bases: one per rf; per-step loads use compile-time imm offsets
  const unsigned short* ab0 = a + (size_t)(wave * 64 + 0 * 16 + llo) * DDIM + (lhi << 3);
  const unsigned short* ab1 = a + (size_t)(wave * 64 + 1 * 16 + llo) * DDIM + (lhi << 3);
  const unsigned short* ab2 = a + (size_t)(wave * 64 + 2 * 16 + llo) * DDIM + (lhi << 3);
  const unsigned short* ab3 = a + (size_t)(wave * 64 + 3 * 16 + llo) * DDIM + (lhi << 3);

  // ---- prologue ----
  issueW(0);
  commitW(0);
  __syncthreads();

  #pragma unroll
  for (int s = 0; s < NSLICE; s++) {
    if (s + 1 < NSLICE) issueW(s + 1);     // w loads in flight across MFMA phase

    #pragma unroll
    for (int half = 0; half < 2; half++) {
      const int koff = (s * 2 + half) * 32;     // compile-time element offset
      short8 af[4], bfr[4];
      af[0] = *reinterpret_cast<const short8*>(ab0 + koff);
      af[1] = *reinterpret_cast<const short8*>(ab1 + koff);
      af[2] = *reinterpret_cast<const short8*>(ab2 + koff);
      af[3] = *reinterpret_cast<const short8*>(ab3 + koff);
      const int kloc = half * 32 + (lhi << 3);
      #pragma unroll
      for (int cf = 0; cf < 4; cf++) {
        const int c = cf * 16 + llo;
        bfr[cf] = *reinterpret_cast<const short8*>(
            &blds[s & 1][c * BK + (kloc ^ ((c & 7) << 3))]);
      }
      #pragma unroll
      for (int rf = 0; rf < 4; rf++)
        #pragma unroll
        for (int cf = 0; cf < 4; cf++)
          acc[rf][cf] = __builtin_amdgcn_mfma_f32_16x16x32_bf16(af[rf], bfr[cf], acc[rf][cf], 0, 0, 0);
    }

    if (s + 1 < NSLICE) commitW((s + 1) & 1);   // write other buffer after MFMAs
    __syncthreads();
  }

  // ---- column-norm reduce ----
  // sum across dgh lanes (same t&3) within wave: masks 4,8,16,32
  #pragma unroll
  for (int msk = 4; msk < 64; msk <<= 1) {
    ssp0 += __shfl_xor(ssp0, msk);
    ssp1 += __shfl_xor(ssp1, msk);
    ssp2 += __shfl_xor(ssp2, msk);
    ssp3 += __shfl_xor(ssp3, msk);
  }
  if (lane < 4) {
    ssred[wave][bc4 + 0] = ssp0;
    ssred[wave][bc4 + 1] = ssp1;
    ssred[wave][bc4 + 2] = ssp2;
    ssred[wave][bc4 + 3] = ssp3;
  }
  __syncthreads();
  if (t < NC) {
    const int p = t >> 4;          // wave-pair covering col t
    const float s = ssred[2 * p][t] + ssred[2 * p + 1][t];
    invwn_sh[t] = 1.f / fmaxf(sqrtf(s), 1e-12f);
  }
  __syncthreads();

  // ---- epilogue: logits -> per-row (max, sumexp) over this chunk's 64 classes ----
  #pragma unroll
  for (int rf = 0; rf < 4; rf++) {
    #pragma unroll
    for (int r = 0; r < 4; r++) {
      const int row = wave * 64 + rf * 16 + (lhi << 2) + r;
      const int lab = (int)label[row];
      float vals[4];
      float mloc = -INFINITY;
      #pragma unroll
      for (int cf = 0; cf < 4; cf++) {
        const int cg = c0 + cf * 16 + llo;
        float cs = acc[rf][cf][r] * invwn_sh[cf * 16 + llo];
        cs = fminf(fmaxf(cs, -1.f), 1.f);
        float lg = 64.f * cs;
        if (cg == lab) { lg = 64.f * (cs - 0.35f); labellogit[row] = lg; }
        if (cg >= CDIM) lg = -INFINITY;
        vals[cf] = lg;
        mloc = fmaxf(mloc, lg);
      }
      float m = mloc;
      #pragma unroll
      for (int msk = 1; msk < 16; msk <<= 1) m = fmaxf(m, __shfl_xor(m, msk));
      float s = 0.f;
      #pragma unroll
      for (int cf = 0; cf < 4; cf++) s += __expf(vals[cf] - m);
      #pragma unroll
      for (int msk = 1; msk < 16; msk <<= 1) s += __shfl_xor(s, msk);
      if (llo == 0) part[(size_t)chunk * BDIM + row] = make_float2(m, s);
    }
  }
}

// ---- kernel 3: per-row online-LSE combine over chunks (part is [chunk][row]) ----
__global__ void k_rowreduce(const float2* __restrict__ part,
                            const float* __restrict__ labellogit,
                            float* __restrict__ rowloss) {
  const int row = blockIdx.x;
  const int tid = threadIdx.x;
  float m = -INFINITY, s = 0.f;
  for (int ch = tid; ch < NCHUNK; ch += 256) {
    float2 p = part[(size_t)ch * BDIM + row];
    float nm = fmaxf(m, p.x);
    s = s * __expf(m - nm) + p.y * __expf(p.x - nm);
    m = nm;
  }
  #pragma unroll
  for (int msk = 1; msk < 64; msk <<= 1) {
    float om = __shfl_xor(m, msk), os = __shfl_xor(s, msk);
    float nm = fmaxf(m, om);
    s = s * __expf(m - nm) + os * __expf(om - nm);
    m = nm;
  }
  __shared__ float sm[4], ssum[4];
  const int wv = tid >> 6, ln = tid & 63;
  if (ln == 0) { sm[wv] = m; ssum[wv] = s; }
  __syncthreads();
  if (tid == 0) {
    float M = sm[0], S = ssum[0];
    #pragma unroll
    for (int i = 1; i < 4; i++) {
      float nm = fmaxf(M, sm[i]);
      S = S * __expf(M - nm) + ssum[i] * __expf(sm[i] - nm);
      M = nm;
    }
    rowloss[row] = M + logf(S) - labellogit[row];
  }
}

// ---- kernel 4: mean over rows -> scalar ----
__global__ void k_mean(const float* __restrict__ rowloss, float* __restrict__ out) {
  const int tid = threadIdx.x;
  float v = rowloss[tid];
  #pragma unroll
  for (int msk = 1; msk < 64; msk <<= 1) v += __shfl_xor(v, msk);
  __shared__ float sred[8];
  if ((tid & 63) == 0) sred[tid >> 6] = v;
  __syncthreads();
  if (tid == 0) {
    float s = 0.f;
    #pragma unroll
    for (int i = 0; i < 8; i++) s += sred[i];
    out[0] = s / (float)BDIM;
  }
}

extern "C" void kernel_launch(void* const* d_in, const int* in_sizes, int n_in,
                              void* d_out, int out_size, void* d_ws, size_t ws_size,
                              hipStream_t stream) {
  const float* input = (const float*)d_in[0];
  const long long* label = (const long long*)d_in[1];
  const float* w = (const float*)d_in[2];
  float* out = (float*)d_out;

  char* ws = (char*)d_ws;
  unsigned short* a_bf16 = (unsigned short*)ws;                       // 512 KB
  float2* part = (float2*)(ws + 512 * 1024);                          // NCHUNK*B*8 = 6.4 MB
  float* labellogit = (float*)(ws + 512 * 1024 + (size_t)BDIM * NCHUNK * sizeof(float2));
  float* rowloss = labellogit + BDIM;

  k_rownorm<<<BDIM, 256, 0, stream>>>(input, a_bf16);
  k_main<<<NCHUNK, 512, 0, stream>>>(a_bf16, w, label, part, labellogit);
  k_rowreduce<<<BDIM, 256, 0, stream>>>(part, labellogit, rowloss);
  k_mean<<<1, BDIM, 0, stream>>>(rowloss, out);
}

// Round 6
// 173.133 us; speedup vs baseline: 1.2771x; 1.2771x over previous
//
#include <hip/hip_runtime.h>
#include <hip/hip_bf16.h>
#include <math.h>

#define BDIM 512
#define DDIM 512
#define CDIM 100000
#define NC 64
#define NCHUNK ((CDIM + NC - 1) / NC)   // 1563

typedef __attribute__((ext_vector_type(8))) short short8;
typedef __attribute__((ext_vector_type(4))) float f32x4;

__device__ __forceinline__ unsigned short f2bf(float f) {
  unsigned int u = __builtin_bit_cast(unsigned int, f);
  u = (u + 0x7FFFu + ((u >> 16) & 1u)) >> 16;   // RNE
  return (unsigned short)u;
}

// ---- kernel 1: L2-normalize feature rows, emit bf16 [B][D] ----
__global__ void k_rownorm(const float* __restrict__ x, unsigned short* __restrict__ a) {
  const int b = blockIdx.x;
  const int tid = threadIdx.x;
  const float* row = x + (size_t)b * DDIM;
  float v0 = row[tid], v1 = row[tid + 256];
  float ss = v0 * v0 + v1 * v1;
  #pragma unroll
  for (int m = 1; m < 64; m <<= 1) ss += __shfl_xor(ss, m);
  __shared__ float sred[4];
  __shared__ float sinv;
  if ((tid & 63) == 0) sred[tid >> 6] = ss;
  __syncthreads();
  if (tid == 0) {
    float s = sred[0] + sred[1] + sred[2] + sred[3];
    sinv = 1.f / fmaxf(sqrtf(s), 1e-12f);
  }
  __syncthreads();
  const float inv = sinv;
  a[(size_t)b * DDIM + tid] = f2bf(v0 * inv);
  a[(size_t)b * DDIM + tid + 256] = f2bf(v1 * inv);
}

// ---- kernel 2: fused colnorm + GEMM + margin + per-chunk LSE partials ----
// Single-shot B-tile staging: the whole 64col x 512k w-slab is loaded in one
// deep burst (16 float4/thread in flight -> BW-bound, not latency-bound),
// converted to bf16 into one 64KB swizzled LDS buffer. One barrier. Then a
// barrier-free fully-unrolled K-loop: af from L2-resident ws, bfr from LDS,
// 256 MFMAs. No vmcnt-FIFO hazard (no w loads after the barrier).
__global__ __launch_bounds__(512, 4)
void k_main(const unsigned short* __restrict__ a,
            const float* __restrict__ w,
            const long long* __restrict__ label,
            float2* __restrict__ part,
            float* __restrict__ labellogit) {
  __shared__ __align__(16) unsigned short blds[NC][DDIM];   // 64 KB, [c][k ^ ((c&7)<<3)]
  __shared__ float ssred[8][NC];                            // 2 KB
  __shared__ float invwn_sh[NC];

  const int t = threadIdx.x;
  const int chunk = blockIdx.x;
  const int c0 = chunk * NC;
  const bool tailblk = (c0 + NC > CDIM);

  const int wave = t >> 6;
  const int lane = t & 63;
  const int lhi = lane >> 4;   // 0..3
  const int llo = lane & 15;   // 0..15

  // staging mapping: thread -> 4 cols (c4..c4+3) x 2 k-octets (tg, tg+32)
  const int c4 = (t & 15) * 4;
  const int tg = t >> 4;       // 0..31

  // ---- single-shot staging: 16 float4 loads, all in flight ----
  float4 p[16];
  if (!tailblk) {
    #pragma unroll
    for (int h = 0; h < 2; h++)
      #pragma unroll
      for (int j = 0; j < 8; j++) {
        const int k = (tg + 32 * h) * 8 + j;
        p[h * 8 + j] = *reinterpret_cast<const float4*>(w + (size_t)k * CDIM + c0 + c4);
      }
  } else {
    #pragma unroll
    for (int h = 0; h < 2; h++)
      #pragma unroll
      for (int j = 0; j < 8; j++) {
        const int k = (tg + 32 * h) * 8 + j;
        #pragma unroll
        for (int cc = 0; cc < 4; cc++)
          p[h * 8 + j][cc] = (c0 + c4 + cc < CDIM) ? w[(size_t)k * CDIM + c0 + c4 + cc] : 0.f;
      }
  }

  float ss0 = 0.f, ss1 = 0.f, ss2 = 0.f, ss3 = 0.f;
  #pragma unroll
  for (int i = 0; i < 16; i++) {
    ss0 += p[i].x * p[i].x; ss1 += p[i].y * p[i].y;
    ss2 += p[i].z * p[i].z; ss3 += p[i].w * p[i].w;
  }

  // bf16 convert + swizzled LDS writes (one ds_write_b128 per col per octet)
  #pragma unroll
  for (int h = 0; h < 2; h++) {
    #pragma unroll
    for (int cc = 0; cc < 4; cc++) {
      const int c = c4 + cc;
      short8 v;
      #pragma unroll
      for (int j = 0; j < 8; j++) v[j] = (short)f2bf(p[h * 8 + j][cc]);
      *reinterpret_cast<short8*>(&blds[c][((tg + 32 * h) * 8) ^ ((c & 7) << 3)]) = v;
    }
  }

  // column sumsq reduce: lanes sharing llo (masks 16,32), then across waves
  #pragma unroll
  for (int msk = 16; msk < 64; msk <<= 1) {
    ss0 += __shfl_xor(ss0, msk);
    ss1 += __shfl_xor(ss1, msk);
    ss2 += __shfl_xor(ss2, msk);
    ss3 += __shfl_xor(ss3, msk);
  }
  if (lane < 16) {
    ssred[wave][c4 + 0] = ss0;
    ssred[wave][c4 + 1] = ss1;
    ssred[wave][c4 + 2] = ss2;
    ssred[wave][c4 + 3] = ss3;
  }
  __syncthreads();                       // blds + ssred ready
  if (t < NC) {
    float s = 0.f;
    #pragma unroll
    for (int i = 0; i < 8; i++) s += ssred[i][t];
    invwn_sh[t] = 1.f / fmaxf(sqrtf(s), 1e-12f);
  }
  __syncthreads();

  // ---- barrier-free K-loop ----
  f32x4 acc[4][4];
  #pragma unroll
  for (int i = 0; i < 4; i++)
    #pragma unroll
    for (int j = 0; j < 4; j++)
      acc[i][j] = (f32x4){0.f, 0.f, 0.f, 0.f};

  const unsigned short* ab0 = a + (size_t)(wave * 64 + 0 * 16 + llo) * DDIM + (lhi << 3);
  const unsigned short* ab1 = a + (size_t)(wave * 64 + 1 * 16 + llo) * DDIM + (lhi << 3);
  const unsigned short* ab2 = a + (size_t)(wave * 64 + 2 * 16 + llo) * DDIM + (lhi << 3);
  const unsigned short* ab3 = a + (size_t)(wave * 64 + 3 * 16 + llo) * DDIM + (lhi << 3);

  #pragma unroll
  for (int step = 0; step < 16; step++) {
    const int koff = step * 32;                 // compile-time imm offsets
    short8 af[4], bfr[4];
    af[0] = *reinterpret_cast<const short8*>(ab0 + koff);
    af[1] = *reinterpret_cast<const short8*>(ab1 + koff);
    af[2] = *reinterpret_cast<const short8*>(ab2 + koff);
    af[3] = *reinterpret_cast<const short8*>(ab3 + koff);
    #pragma unroll
    for (int cf = 0; cf < 4; cf++) {
      const int c = cf * 16 + llo;
      bfr[cf] = *reinterpret_cast<const short8*>(
          &blds[c][(koff + (lhi << 3)) ^ ((c & 7) << 3)]);
    }
    #pragma unroll
    for (int rf = 0; rf < 4; rf++)
      #pragma unroll
      for (int cf = 0; cf < 4; cf++)
        acc[rf][cf] = __builtin_amdgcn_mfma_f32_16x16x32_bf16(af[rf], bfr[cf], acc[rf][cf], 0, 0, 0);
  }

  // ---- epilogue: logits -> per-row (max, sumexp) over this chunk's 64 classes ----
  #pragma unroll
  for (int rf = 0; rf < 4; rf++) {
    #pragma unroll
    for (int r = 0; r < 4; r++) {
      const int row = wave * 64 + rf * 16 + (lhi << 2) + r;
      const int lab = (int)label[row];
      float vals[4];
      float mloc = -INFINITY;
      #pragma unroll
      for (int cf = 0; cf < 4; cf++) {
        const int cg = c0 + cf * 16 + llo;
        float cs = acc[rf][cf][r] * invwn_sh[cf * 16 + llo];
        cs = fminf(fmaxf(cs, -1.f), 1.f);
        float lg = 64.f * cs;
        if (cg == lab) { lg = 64.f * (cs - 0.35f); labellogit[row] = lg; }
        if (cg >= CDIM) lg = -INFINITY;
        vals[cf] = lg;
        mloc = fmaxf(mloc, lg);
      }
      float m = mloc;
      #pragma unroll
      for (int msk = 1; msk < 16; msk <<= 1) m = fmaxf(m, __shfl_xor(m, msk));
      float s = 0.f;
      #pragma unroll
      for (int cf = 0; cf < 4; cf++) s += __expf(vals[cf] - m);
      #pragma unroll
      for (int msk = 1; msk < 16; msk <<= 1) s += __shfl_xor(s, msk);
      if (llo == 0) part[(size_t)chunk * BDIM + row] = make_float2(m, s);
    }
  }
}

// ---- kernel 3: per-row online-LSE combine over chunks (part is [chunk][row]) ----
__global__ void k_rowreduce(const float2* __restrict__ part,
                            const float* __restrict__ labellogit,
                            float* __restrict__ rowloss) {
  const int row = blockIdx.x;
  const int tid = threadIdx.x;
  float m = -INFINITY, s = 0.f;
  for (int ch = tid; ch < NCHUNK; ch += 256) {
    float2 p = part[(size_t)ch * BDIM + row];
    float nm = fmaxf(m, p.x);
    s = s * __expf(m - nm) + p.y * __expf(p.x - nm);
    m = nm;
  }
  #pragma unroll
  for (int msk = 1; msk < 64; msk <<= 1) {
    float om = __shfl_xor(m, msk), os = __shfl_xor(s, msk);
    float nm = fmaxf(m, om);
    s = s * __expf(m - nm) + os * __expf(om - nm);
    m = nm;
  }
  __shared__ float sm[4], ssum[4];
  const int wv = tid >> 6, ln = tid & 63;
  if (ln == 0) { sm[wv] = m; ssum[wv] = s; }
  __syncthreads();
  if (tid == 0) {
    float M = sm[0], S = ssum[0];
    #pragma unroll
    for (int i = 1; i < 4; i++) {
      float nm = fmaxf(M, sm[i]);
      S = S * __expf(M - nm) + ssum[i] * __expf(sm[i] - nm);
      M = nm;
    }
    rowloss[row] = M + logf(S) - labellogit[row];
  }
}

// ---- kernel 4: mean over rows -> scalar ----
__global__ void k_mean(const float* __restrict__ rowloss, float* __restrict__ out) {
  const int tid = threadIdx.x;
  float v = rowloss[tid];
  #pragma unroll
  for (int msk = 1; msk < 64; msk <<= 1) v += __shfl_xor(v, msk);
  __shared__ float sred[8];
  if ((tid & 63) == 0) sred[tid >> 6] = v;
  __syncthreads();
  if (tid == 0) {
    float s = 0.f;
    #pragma unroll
    for (int i = 0; i < 8; i++) s += sred[i];
    out[0] = s / (float)BDIM;
  }
}

extern "C" void kernel_launch(void* const* d_in, const int* in_sizes, int n_in,
                              void* d_out, int out_size, void* d_ws, size_t ws_size,
                              hipStream_t stream) {
  const float* input = (const float*)d_in[0];
  const long long* label = (const long long*)d_in[1];
  const float* w = (const float*)d_in[2];
  float* out = (float*)d_out;

  char* ws = (char*)d_ws;
  unsigned short* a_bf16 = (unsigned short*)ws;                       // 512 KB
  float2* part = (float2*)(ws + 512 * 1024);                          // NCHUNK*B*8 = 6.4 MB
  float* labellogit = (float*)(ws + 512 * 1024 + (size_t)BDIM * NCHUNK * sizeof(float2));
  float* rowloss = labellogit + BDIM;

  k_rownorm<<<BDIM, 256, 0, stream>>>(input, a_bf16);
  k_main<<<NCHUNK, 512, 0, stream>>>(a_bf16, w, label, part, labellogit);
  k_rowreduce<<<BDIM, 256, 0, stream>>>(part, labellogit, rowloss);
  k_mean<<<1, BDIM, 0, stream>>>(rowloss, out);
}